// Round 7
// baseline (838.909 us; speedup 1.0000x reference)
//
#include <hip/hip_runtime.h>
#include <stdint.h>

#define E_ 8
#define D_ 1024
#define H_ 2048
#define O_ 1024
#define B_ 4096
#define GTOT (B_ * 2)        // total compact rows (every token to exactly 2 experts)
#define GPAD (GTOT + 256)    // pad: 256-row GEMM tiles may over-read up to 255 rows past count
#define MT_MAX 16            // 128-row tiles per expert (legacy kernel)
#define MT256 8              // 256-row tiles per expert (8-phase kernel)

typedef __attribute__((ext_vector_type(8))) __bf16 bf16x8;
typedef __attribute__((ext_vector_type(4))) float f32x4;
typedef unsigned short u16;
typedef __attribute__((ext_vector_type(4))) u16 u16x4;
typedef __attribute__((ext_vector_type(8))) u16 u16x8;

__device__ __forceinline__ u16 f2bf(float f) {
    union { float f; uint32_t u; } v; v.f = f;
    uint32_t u = v.u;
    return (u16)((u + 0x7FFFu + ((u >> 16) & 1u)) >> 16);   // RNE
}

// async global->LDS, 16B per lane; LDS dest = wave-uniform base + lane*16
__device__ __forceinline__ void gl2lds16(const void* g, void* lds) {
    __builtin_amdgcn_global_load_lds(
        (__attribute__((address_space(1))) void*)(uintptr_t)g,
        (__attribute__((address_space(3))) void*)(uint32_t)(uintptr_t)lds,
        16, 0, 0);
}

struct XPtrs { const float* p[8]; };

// top-2 + softmax for one token given reduced fp64 logits (lane 0 only).
__device__ __forceinline__ void gate_finish(int b, const double* acc, const float* __restrict__ gb,
                                            int* __restrict__ t2i, float* __restrict__ t2w) {
    float lg[8];
#pragma unroll
    for (int e = 0; e < 8; ++e) lg[e] = (float)acc[e] + gb[e];
    int i0 = 0;
#pragma unroll
    for (int e = 1; e < 8; ++e) if (lg[e] > lg[i0]) i0 = e;   // strict > : lowest idx on tie
    int i1 = -1;
#pragma unroll
    for (int e = 0; e < 8; ++e) {
        if (e == i0) continue;
        if (i1 < 0 || lg[e] > lg[i1]) i1 = e;
    }
    float ex = expf(lg[i1] - lg[i0]);
    float w0 = 1.0f / (1.0f + ex);
    t2i[b * 2 + 0] = i0; t2i[b * 2 + 1] = i1;
    t2w[b * 2 + 0] = w0; t2w[b * 2 + 1] = ex * w0;
}

// ---------------- gating: 2 tokens per wave (gw row reuse), fp64 accumulation ----------------
__global__ void __launch_bounds__(256) gate_kernel(XPtrs xs, const float* __restrict__ gw,
                                                   const float* __restrict__ gb,
                                                   int* __restrict__ t2i, float* __restrict__ t2w) {
    int wave = threadIdx.x >> 6;
    int lane = threadIdx.x & 63;
    int b0 = blockIdx.x * 8 + wave * 2;
    double acc0[8], acc1[8];
#pragma unroll
    for (int e = 0; e < 8; ++e) { acc0[e] = 0.0; acc1[e] = 0.0; }
    for (int ep = 0; ep < 8; ++ep) {
        const float* xr0 = xs.p[ep] + (size_t)b0 * D_;
        const float* xr1 = xr0 + D_;
        for (int t = 0; t < D_ / 64; ++t) {
            int d = t * 64 + lane;
            float v0 = xr0[d];
            float v1 = xr1[d];
            const float* g = gw + ((size_t)(ep * D_ + d)) * 8;
#pragma unroll
            for (int e = 0; e < 8; ++e) {
                double ge = (double)g[e];
                acc0[e] += (double)v0 * ge;
                acc1[e] += (double)v1 * ge;
            }
        }
    }
#pragma unroll
    for (int e = 0; e < 8; ++e) {
        for (int off = 32; off > 0; off >>= 1) {
            acc0[e] += __shfl_xor(acc0[e], off, 64);
            acc1[e] += __shfl_xor(acc1[e], off, 64);
        }
    }
    if (lane == 0) {
        gate_finish(b0 + 0, acc0, gb, t2i, t2w);
        gate_finish(b0 + 1, acc1, gb, t2i, t2w);
    }
}

// ---------------- routing: counts -> offsets (single block) ----------------
__global__ void __launch_bounds__(256) route_build(const int* __restrict__ t2i,
                                                   int* __restrict__ offs, int* __restrict__ cursor) {
    __shared__ int cnt[8];
    int t = threadIdx.x;
    if (t < 8) cnt[t] = 0;
    __syncthreads();
    for (int i = t; i < B_ * 2; i += 256) atomicAdd(&cnt[t2i[i]], 1);
    __syncthreads();
    if (t == 0) {
        int run = 0;
        for (int e = 0; e < 8; ++e) { offs[e] = run; cursor[e] = run; run += cnt[e]; }
        offs[8] = run;
    }
}

// ---------------- fused scatter + gather ----------------
__global__ void __launch_bounds__(256) scatter_gather(XPtrs xs, const int* __restrict__ t2i,
                                                      int* __restrict__ cursor, int* __restrict__ slot,
                                                      u16* __restrict__ A1) {
    int b = blockIdx.x;
    int t = threadIdx.x;
    __shared__ int gsh[2];
    int e0 = t2i[b * 2 + 0], e1 = t2i[b * 2 + 1];
    if (t == 0) {
        int g0 = atomicAdd(&cursor[e0], 1);
        int g1 = atomicAdd(&cursor[e1], 1);
        gsh[0] = g0; gsh[1] = g1;
        slot[b * 2 + 0] = g0; slot[b * 2 + 1] = g1;
    }
    __syncthreads();
    int g0 = gsh[0], g1 = gsh[1];
    float4 v0 = ((const float4*)(xs.p[e0] + (size_t)b * D_))[t];
    float4 v1 = ((const float4*)(xs.p[e1] + (size_t)b * D_))[t];
    u16x4 o0, o1;
    o0.x = f2bf(v0.x); o0.y = f2bf(v0.y); o0.z = f2bf(v0.z); o0.w = f2bf(v0.w);
    o1.x = f2bf(v1.x); o1.y = f2bf(v1.y); o1.z = f2bf(v1.z); o1.w = f2bf(v1.w);
    ((u16x4*)(A1 + (size_t)g0 * D_))[t] = o0;
    ((u16x4*)(A1 + (size_t)g1 * D_))[t] = o1;
}

// ---------------- weight transpose-convert: [E][K][N] f32 -> [E][N][K] bf16 ----------------
__global__ void __launch_bounds__(256) wconv(const float* __restrict__ w, u16* __restrict__ wt,
                                             int K, int N) {
    __shared__ float tile[64][33];
    int e = blockIdx.z;
    int n0 = blockIdx.x * 32, k0 = blockIdx.y * 64;
    int tid = threadIdx.x;
    int tx = tid & 31, ty = tid >> 5;
    const float* wp = w + (size_t)e * K * N + (size_t)k0 * N + n0;
#pragma unroll
    for (int r = 0; r < 8; ++r)
        tile[ty + r * 8][tx] = wp[(size_t)(ty + r * 8) * N + tx];
    __syncthreads();
    int n = tid >> 3, kq = tid & 7;
    u16x8 o;
#pragma unroll
    for (int i = 0; i < 8; ++i) o[i] = f2bf(tile[kq * 8 + i][n]);
    u16* op = wt + (size_t)e * N * K + (size_t)(n0 + n) * K + k0 + kq * 8;
    *(u16x8*)op = o;
}

// ================= 256x256 8-phase expert GEMM (T2+T3+T4+T5) =================
// BM=BN=256, BK=64, 512 thr = 8 waves (2M x 4N), per-wave C = 128x64.
// LDS 128KB dynamic: [A|B] x [dbuf 2] x [half 2] x [128 rows][64 k] bf16.
// Phases = block-level C-quadrants (mh,nh): each phase touches exactly A-half mh
// and B-half nh -> half-tile lifetimes allow staging 3 half-tiles ahead with ONE
// counted vmcnt(4) per K-tile (never 0 until the tail; T4).
// Stage schedule at tile T: ph1 A1(T+1) | ph2 B1(T+1) | ph3 A0(T+2) | ph4 B0(T+2).
// vmcnt ledger (2 loads/stage/thread): entering ph4-wait, 12 outstanding;
// vmcnt(4) retires oldest 8 = ALL of tile T+1; leaves {A0,B0}(T+2). Audited r5/r6.
// Race audit: every stage overwrites a region whose last ds_read completed >=2
// barriers earlier (A0/B0 of same dbuf slot re-staged in ph3/ph4 after ph1 reads).
// Bank swizzle: phys chunk = logical chunk ^ (row&7); read addr uses the same
// involution (rh&7 == l15&7 since all row offsets are multiples of 8). Staging:
// linear LDS dest + inverse-swizzled global source (rule #21).
__global__ void __launch_bounds__(512, 2) expert_gemm256(const u16* __restrict__ A,
                                                         const u16* __restrict__ Wt,
                                                         const float* __restrict__ bias,
                                                         u16* __restrict__ outB,
                                                         const int* __restrict__ offs,
                                                         int K, int N) {
    int bid = blockIdx.x;
    int e = bid & 7;                     // XCD affinity: expert e -> XCD e
    int j = bid >> 3;
    int mt = j & (MT256 - 1);            // mt fastest: expert's A panel stays hot in its L2
    int nt = j >> 3;
    int row0 = offs[e];
    int cnt = offs[e + 1] - row0;
    if (mt * 256 >= cnt) return;

    extern __shared__ __align__(16) u16 smem[];
    u16* sA = smem;                      // 2*2*128*64 = 32768 u16 (64KB)
    u16* sB = smem + 32768;

    int tid = threadIdx.x;
    int wave = tid >> 6, lane = tid & 63;
    int wm = wave >> 2;                  // 0..1  (M dim)
    int wn = wave & 3;                   // 0..3  (N dim)
    int l15 = lane & 15, quad = lane >> 4;
    int swz = l15 & 7;                   // read-side row XOR for chunk swizzle

    const u16* Abase = A + (size_t)(row0 + mt * 256) * K;
    const u16* Bbase = Wt + ((size_t)e * N + (size_t)nt * 256) * K;
    int NT = K >> 6;                     // K-tiles of 64

    // stage one half-tile (128 rows x 64 k) = 1024 16B-chunks by 512 threads x 2 rounds.
    auto stageA = [&](int tile, int half) {
        if (tile < NT) {
            u16* dst = sA + (((tile & 1) * 2 + half) << 13);
            const u16* gs = Abase + (size_t)(half * 128) * K + tile * 64;
#pragma unroll
            for (int rr = 0; rr < 2; ++rr) {
                int liB = rr * 512 + wave * 64;          // wave-uniform
                int li = liB + lane;
                int r = li >> 3;
                int lc = (li & 7) ^ (r & 7);
                gl2lds16(gs + (size_t)r * K + lc * 8, dst + liB * 8);
            }
        }
    };
    auto stageB = [&](int tile, int half) {
        if (tile < NT) {
            u16* dst = sB + (((tile & 1) * 2 + half) << 13);
            const u16* gs = Bbase + (size_t)(half * 128) * K + tile * 64;
#pragma unroll
            for (int rr = 0; rr < 2; ++rr) {
                int liB = rr * 512 + wave * 64;
                int li = liB + lane;
                int r = li >> 3;
                int lc = (li & 7) ^ (r & 7);
                gl2lds16(gs + (size_t)r * K + lc * 8, dst + liB * 8);
            }
        }
    };

    f32x4 acc[2][2][4][2];
#pragma unroll
    for (int a = 0; a < 2; ++a)
#pragma unroll
        for (int b = 0; b < 2; ++b)
#pragma unroll
            for (int c = 0; c < 4; ++c)
#pragma unroll
                for (int dd = 0; dd < 2; ++dd) acc[a][b][c][dd] = (f32x4){0.f, 0.f, 0.f, 0.f};

    // prologue: tile0 all 4 halves + tile1 halves0 -> oldest 8 loads = tile0 complete
    stageA(0, 0); stageB(0, 0); stageA(0, 1); stageB(0, 1);
    stageA(1, 0); stageB(1, 0);
    __builtin_amdgcn_s_waitcnt(0x74);    // vmcnt(4) lgkmcnt(0): tile0 landed, 2 half-tiles in flight
    __builtin_amdgcn_s_barrier();

    bf16x8 af[4][2];                     // A frags for current mh (4 row16 x 2 kc)
    bf16x8 bfr[2][2][2];                 // B frags [nh][fn][kc], both halves kept

    for (int T = 0; T < NT; ++T) {
        int d = T & 1;
        const u16* aB0 = sA + ((d * 2 + 0) << 13);
        const u16* aB1 = sA + ((d * 2 + 1) << 13);
        const u16* bB0 = sB + ((d * 2 + 0) << 13);
        const u16* bB1 = sB + ((d * 2 + 1) << 13);

        // ---- phase 1: quadrant (mh=0, nh=0); reads A0(8)+B0(4); stage A1(T+1) ----
#pragma unroll
        for (int fm = 0; fm < 4; ++fm) {
            int rh = wm * 64 + fm * 16 + l15;
#pragma unroll
            for (int kc = 0; kc < 2; ++kc)
                af[fm][kc] = *(const bf16x8*)(aB0 + rh * 64 + (((kc << 2) | quad) ^ swz) * 8);
        }
#pragma unroll
        for (int fn = 0; fn < 2; ++fn) {
            int rh = wn * 32 + fn * 16 + l15;
#pragma unroll
            for (int kc = 0; kc < 2; ++kc)
                bfr[0][fn][kc] = *(const bf16x8*)(bB0 + rh * 64 + (((kc << 2) | quad) ^ swz) * 8);
        }
        stageA(T + 1, 1);
        __builtin_amdgcn_s_barrier();
        __builtin_amdgcn_s_setprio(1);
#pragma unroll
        for (int fm = 0; fm < 4; ++fm)
#pragma unroll
            for (int fn = 0; fn < 2; ++fn)
#pragma unroll
                for (int kc = 0; kc < 2; ++kc)
                    acc[0][0][fm][fn] = __builtin_amdgcn_mfma_f32_16x16x32_bf16(
                        af[fm][kc], bfr[0][fn][kc], acc[0][0][fm][fn], 0, 0, 0);
        __builtin_amdgcn_s_setprio(0);
        __builtin_amdgcn_s_barrier();

        // ---- phase 2: (0,1); reads B1(4); stage B1(T+1); A regs reused ----
#pragma unroll
        for (int fn = 0; fn < 2; ++fn) {
            int rh = wn * 32 + fn * 16 + l15;
#pragma unroll
            for (int kc = 0; kc < 2; ++kc)
                bfr[1][fn][kc] = *(const bf16x8*)(bB1 + rh * 64 + (((kc << 2) | quad) ^ swz) * 8);
        }
        stageB(T + 1, 1);
        __builtin_amdgcn_s_barrier();
        __builtin_amdgcn_s_setprio(1);
#pragma unroll
        for (int fm = 0; fm < 4; ++fm)
#pragma unroll
            for (int fn = 0; fn < 2; ++fn)
#pragma unroll
                for (int kc = 0; kc < 2; ++kc)
                    acc[0][1][fm][fn] = __builtin_amdgcn_mfma_f32_16x16x32_bf16(
                        af[fm][kc], bfr[1][fn][kc], acc[0][1][fm][fn], 0, 0, 0);
        __builtin_amdgcn_s_setprio(0);
        __builtin_amdgcn_s_barrier();

        // ---- phase 3: (1,0); reads A1(8) (A0 regs dead); stage A0(T+2) ----
#pragma unroll
        for (int fm = 0; fm < 4; ++fm) {
            int rh = wm * 64 + fm * 16 + l15;
#pragma unroll
            for (int kc = 0; kc < 2; ++kc)
                af[fm][kc] = *(const bf16x8*)(aB1 + rh * 64 + (((kc << 2) | quad) ^ swz) * 8);
        }
        stageA(T + 2, 0);
        __builtin_amdgcn_s_barrier();
        __builtin_amdgcn_s_setprio(1);
#pragma unroll
        for (int fm = 0; fm < 4; ++fm)
#pragma unroll
            for (int fn = 0; fn < 2; ++fn)
#pragma unroll
                for (int kc = 0; kc < 2; ++kc)
                    acc[1][0][fm][fn] = __builtin_amdgcn_mfma_f32_16x16x32_bf16(
                        af[fm][kc], bfr[0][fn][kc], acc[1][0][fm][fn], 0, 0, 0);
        __builtin_amdgcn_s_setprio(0);
        __builtin_amdgcn_s_barrier();

        // ---- phase 4: (1,1); no reads; stage B0(T+2); counted vmcnt, then barrier ----
        stageB(T + 2, 0);
        __builtin_amdgcn_s_barrier();
        __builtin_amdgcn_s_setprio(1);
#pragma unroll
        for (int fm = 0; fm < 4; ++fm)
#pragma unroll
            for (int fn = 0; fn < 2; ++fn)
#pragma unroll
                for (int kc = 0; kc < 2; ++kc)
                    acc[1][1][fm][fn] = __builtin_amdgcn_mfma_f32_16x16x32_bf16(
                        af[fm][kc], bfr[1][fn][kc], acc[1][1][fm][fn], 0, 0, 0);
        __builtin_amdgcn_s_setprio(0);
        if (T + 2 < NT) __builtin_amdgcn_s_waitcnt(0x74);   // vmcnt(4): tile T+1 fully landed
        else            __builtin_amdgcn_s_waitcnt(0x70);   // tail: drain everything
        __builtin_amdgcn_s_barrier();
    }

    // epilogue: C/D layout col=lane&15, row=quad*4+reg; bias+relu, bf16 out
#pragma unroll
    for (int mh = 0; mh < 2; ++mh)
#pragma unroll
        for (int nh = 0; nh < 2; ++nh)
#pragma unroll
            for (int fn = 0; fn < 2; ++fn) {
                int col = nt * 256 + nh * 128 + wn * 32 + fn * 16 + l15;
                float bv = bias[e * N + col];
#pragma unroll
                for (int fm = 0; fm < 4; ++fm) {
                    int rloc = mt * 256 + mh * 128 + wm * 64 + fm * 16 + quad * 4;
#pragma unroll
                    for (int r = 0; r < 4; ++r) {
                        if (rloc + r < cnt) {
                            float v = acc[mh][nh][fm][fn][r] + bv;
                            v = fmaxf(v, 0.f);
                            outB[(size_t)(row0 + rloc + r) * N + col] = f2bf(v);
                        }
                    }
                }
            }
}

// ---------------- legacy 128x128 expert GEMM (kept for layer 3: N=1024) ----------------
__global__ void __launch_bounds__(256) expert_gemm(const u16* __restrict__ A, const u16* __restrict__ Wt,
                                                   const float* __restrict__ bias,
                                                   u16* __restrict__ outB, float* __restrict__ outF,
                                                   const int* __restrict__ offs, int K, int N, int relu) {
    int bid = blockIdx.x;
    int e = bid & 7;
    int j = bid >> 3;
    int mt = j & (MT_MAX - 1);
    int nt = j >> 4;
    int row0 = offs[e];
    int cnt = offs[e + 1] - row0;
    if (mt * 128 >= cnt) return;

    __shared__ __align__(16) u16 sA[3][128 * 32];
    __shared__ __align__(16) u16 sB[3][128 * 32];

    int tid = threadIdx.x;
    int wave = tid >> 6, lane = tid & 63;
    int wm = wave & 1, wn = wave >> 1;
    int l15 = lane & 15, quad = lane >> 4;
    int rsub = lane >> 2;
    int koff = (((lane & 3) ^ (rsub & 3) ^ ((rsub >> 2) & 3)) * 8);
    int physOff = (quad ^ (l15 & 3) ^ ((l15 >> 2) & 3)) * 8;

    f32x4 acc[4][4];
#pragma unroll
    for (int i = 0; i < 4; ++i)
#pragma unroll
        for (int jj = 0; jj < 4; ++jj) acc[i][jj] = (f32x4){0.f, 0.f, 0.f, 0.f};

    const u16* Abase = A + (size_t)(row0 + mt * 128) * K;
    const u16* Bbase = Wt + ((size_t)e * N + (size_t)nt * 128) * K;

    int kSteps = K / 32;

    auto issue = [&](int ks, int bufIdx) {
        int k0 = ks * 32;
        u16* dA = &sA[bufIdx][0];
        u16* dB = &sB[bufIdx][0];
#pragma unroll
        for (int c = 0; c < 2; ++c) {
            int ch = wave * 2 + c;
            int r = ch * 16 + rsub;
            gl2lds16(Abase + (size_t)r * K + k0 + koff, dA + ch * 512);
            gl2lds16(Bbase + (size_t)r * K + k0 + koff, dB + ch * 512);
        }
    };

    issue(0, 0);
    issue(1, 1);
    int bc = 0, bi = 2;
    for (int ks = 0; ks < kSteps; ++ks) {
        if (ks + 1 < kSteps) __builtin_amdgcn_s_waitcnt(0x74);
        else                 __builtin_amdgcn_s_waitcnt(0x70);
        __builtin_amdgcn_s_barrier();
        if (ks + 2 < kSteps) issue(ks + 2, bi);

        const u16* a_ = &sA[bc][0];
        const u16* b_ = &sB[bc][0];
        bf16x8 af[4], bfr[4];
#pragma unroll
        for (int tm = 0; tm < 4; ++tm) {
            int row = wm * 64 + tm * 16 + l15;
            af[tm] = *(const bf16x8*)(a_ + row * 32 + physOff);
        }
#pragma unroll
        for (int tn = 0; tn < 4; ++tn) {
            int row = wn * 64 + tn * 16 + l15;
            bfr[tn] = *(const bf16x8*)(b_ + row * 32 + physOff);
        }
        __builtin_amdgcn_s_setprio(1);
#pragma unroll
        for (int tm = 0; tm < 4; ++tm)
#pragma unroll
            for (int tn = 0; tn < 4; ++tn)
                acc[tm][tn] = __builtin_amdgcn_mfma_f32_16x16x32_bf16(af[tm], bfr[tn], acc[tm][tn], 0, 0, 0);
        __builtin_amdgcn_s_setprio(0);

        bc = (bc == 2) ? 0 : bc + 1;
        bi = (bi == 2) ? 0 : bi + 1;
    }

    size_t gm0 = (size_t)row0 + (size_t)mt * 128 + (size_t)wm * 64;
    int lm0 = mt * 128 + wm * 64;
    int n0 = nt * 128 + wn * 64;
#pragma unroll
    for (int tn = 0; tn < 4; ++tn) {
        int col = n0 + tn * 16 + l15;
        float bv = bias[e * N + col];
#pragma unroll
        for (int tm = 0; tm < 4; ++tm) {
#pragma unroll
            for (int r = 0; r < 4; ++r) {
                int rr = tm * 16 + quad * 4 + r;
                if (lm0 + rr < cnt) {
                    float v = acc[tm][tn][r] + bv;
                    if (relu) v = fmaxf(v, 0.f);
                    if (outB) outB[(gm0 + rr) * N + col] = f2bf(v);
                    else      outF[(gm0 + rr) * N + col] = v;
                }
            }
        }
    }
}

// ---------------- combine: out[b] = w0*eo[slot0] + w1*eo[slot1] ----------------
__global__ void __launch_bounds__(256) combine_out(const float* __restrict__ eo, const int* __restrict__ slot,
                                                   const float* __restrict__ t2w, float* __restrict__ out) {
    int b = blockIdx.x, t = threadIdx.x;
    int g0 = slot[b * 2 + 0], g1 = slot[b * 2 + 1];
    float w0 = t2w[b * 2 + 0], w1 = t2w[b * 2 + 1];
    float4 va = ((const float4*)(eo + (size_t)g0 * O_))[t];
    float4 vc = ((const float4*)(eo + (size_t)g1 * O_))[t];
    float4 r;
    r.x = w0 * va.x + w1 * vc.x;
    r.y = w0 * va.y + w1 * vc.y;
    r.z = w0 * va.z + w1 * vc.z;
    r.w = w0 * va.w + w1 * vc.w;
    ((float4*)(out + (size_t)b * O_))[t] = r;
}

extern "C" void kernel_launch(void* const* d_in, const int* in_sizes, int n_in,
                              void* d_out, int out_size, void* d_ws, size_t ws_size,
                              hipStream_t stream) {
    (void)in_sizes; (void)n_in; (void)out_size; (void)ws_size;

    // one-time: raise dynamic-LDS cap for the 128KB kernel (default cap is 64KB).
    // host-side, immediate, not stream-ordered -> graph-capture safe.
    static bool lds_attr_set = false;
    if (!lds_attr_set) {
        hipFuncSetAttribute((const void*)expert_gemm256,
                            hipFuncAttributeMaxDynamicSharedMemorySize, 131072);
        lds_attr_set = true;
    }

    XPtrs xp;
    for (int i = 0; i < 8; ++i) xp.p[i] = (const float*)d_in[i];
    const float* gate_w = (const float*)d_in[8];
    const float* gate_b = (const float*)d_in[9];
    const float* w_in  = (const float*)d_in[10];
    const float* b_in  = (const float*)d_in[11];
    const float* w_h   = (const float*)d_in[12];
    const float* b_h   = (const float*)d_in[13];
    const float* w_out = (const float*)d_in[14];
    const float* b_out = (const float*)d_in[15];
    float* out = (float*)d_out;

    char* ws = (char*)d_ws;
    size_t off = 0;
    auto alloc = [&](size_t b) { size_t o = off; off += (b + 255) & ~(size_t)255; return o; };

    size_t t2i_o  = alloc((size_t)B_ * 2 * 4);
    size_t t2w_o  = alloc((size_t)B_ * 2 * 4);
    size_t slot_o = alloc((size_t)B_ * 2 * 4);
    size_t offs_o = alloc(16 * 4);
    size_t cur_o  = alloc(8 * 4);
    size_t A1_o   = alloc((size_t)GPAD * D_ * 2);      // bf16 gathered inputs
    size_t h1_o   = alloc((size_t)GPAD * H_ * 2);      // bf16
    size_t h2_o   = alloc((size_t)GPAD * H_ * 2);      // bf16
    size_t wtin_o = alloc((size_t)E_ * H_ * D_ * 2);   // bf16 [e][n][k]
    size_t wth_o  = alloc((size_t)E_ * H_ * H_ * 2);
    size_t wtout_o= alloc((size_t)E_ * O_ * H_ * 2);
    size_t eo_o   = A1_o;   // alias: A1+h1 dead by the time layer-3 writes eo

    int*   t2i  = (int*)(ws + t2i_o);
    float* t2w  = (float*)(ws + t2w_o);
    int*   slot = (int*)(ws + slot_o);
    int*   offs = (int*)(ws + offs_o);
    int*   cur  = (int*)(ws + cur_o);
    u16*   A1   = (u16*)(ws + A1_o);
    u16*   h1   = (u16*)(ws + h1_o);
    u16*   h2   = (u16*)(ws + h2_o);
    u16*   wtin = (u16*)(ws + wtin_o);
    u16*   wth  = (u16*)(ws + wth_o);
    u16*   wtout= (u16*)(ws + wtout_o);
    float* eo   = (float*)(ws + eo_o);

    // gating + routing (scatter+gather fused)
    hipLaunchKernelGGL(gate_kernel, dim3(B_ / 8), dim3(256), 0, stream, xp, gate_w, gate_b, t2i, t2w);
    hipLaunchKernelGGL(route_build, dim3(1), dim3(256), 0, stream, t2i, offs, cur);
    hipLaunchKernelGGL(scatter_gather, dim3(B_), dim3(256), 0, stream, xp, t2i, cur, slot, A1);

    // weight convert+transpose (fp32 [E][K][N] -> bf16 [E][N][K])
    hipLaunchKernelGGL(wconv, dim3(H_ / 32, D_ / 64, E_), dim3(256), 0, stream, w_in, wtin, D_, H_);
    hipLaunchKernelGGL(wconv, dim3(H_ / 32, H_ / 64, E_), dim3(256), 0, stream, w_h, wth, H_, H_);
    hipLaunchKernelGGL(wconv, dim3(O_ / 32, H_ / 64, E_), dim3(256), 0, stream, w_out, wtout, H_, O_);

    // expert MLP: layers 1+2 on the 256^2 8-phase kernel (128KB dynamic LDS),
    // layer 3 (N=1024 -> only 128 active 256-blocks = half chip) stays on 128^2.
    hipLaunchKernelGGL(expert_gemm256, dim3(E_ * MT256 * (H_ / 256)), dim3(512), 131072, stream,
                       A1, wtin, b_in, h1, offs, D_, H_);
    hipLaunchKernelGGL(expert_gemm256, dim3(E_ * MT256 * (H_ / 256)), dim3(512), 131072, stream,
                       h1, wth, b_h, h2, offs, H_, H_);
    hipLaunchKernelGGL(expert_gemm, dim3(E_ * MT_MAX * (O_ / 128)), dim3(256), 0, stream,
                       h2, wtout, b_out, (u16*)nullptr, eo, offs, H_, O_, 0);

    // weighted combine -> out (fully written, no zero-init needed)
    hipLaunchKernelGGL(combine_out, dim3(B_), dim3(256), 0, stream, eo, slot, t2w, out);
}

// Round 10
// 827.561 us; speedup vs baseline: 1.0137x; 1.0137x over previous
//
#include <hip/hip_runtime.h>
#include <stdint.h>

#define E_ 8
#define D_ 1024
#define H_ 2048
#define O_ 1024
#define B_ 4096
#define GTOT (B_ * 2)        // total compact rows (every token to exactly 2 experts)
#define GPAD (GTOT + 256)    // pad: 256-row GEMM tiles may over-read up to 255 rows past count
#define MT_MAX 16            // 128-row tiles per expert (legacy kernel)
#define MT256 8              // 256-row tiles per expert (8-phase kernel)

typedef __attribute__((ext_vector_type(8))) __bf16 bf16x8;
typedef __attribute__((ext_vector_type(4))) float f32x4;
typedef unsigned short u16;
typedef __attribute__((ext_vector_type(4))) u16 u16x4;
typedef __attribute__((ext_vector_type(8))) u16 u16x8;

__device__ __forceinline__ u16 f2bf(float f) {
    union { float f; uint32_t u; } v; v.f = f;
    uint32_t u = v.u;
    return (u16)((u + 0x7FFFu + ((u >> 16) & 1u)) >> 16);   // RNE
}

// async global->LDS, 16B per lane; LDS dest = wave-uniform base + lane*16
__device__ __forceinline__ void gl2lds16(const void* g, void* lds) {
    __builtin_amdgcn_global_load_lds(
        (__attribute__((address_space(1))) void*)(uintptr_t)g,
        (__attribute__((address_space(3))) void*)(uint32_t)(uintptr_t)lds,
        16, 0, 0);
}

struct XPtrs { const float* p[8]; };

// top-2 + softmax for one token given reduced fp64 logits (lane 0 only).
__device__ __forceinline__ void gate_finish(int b, const double* acc, const float* __restrict__ gb,
                                            int* __restrict__ t2i, float* __restrict__ t2w) {
    float lg[8];
#pragma unroll
    for (int e = 0; e < 8; ++e) lg[e] = (float)acc[e] + gb[e];
    int i0 = 0;
#pragma unroll
    for (int e = 1; e < 8; ++e) if (lg[e] > lg[i0]) i0 = e;   // strict > : lowest idx on tie
    int i1 = -1;
#pragma unroll
    for (int e = 0; e < 8; ++e) {
        if (e == i0) continue;
        if (i1 < 0 || lg[e] > lg[i1]) i1 = e;
    }
    float ex = expf(lg[i1] - lg[i0]);
    float w0 = 1.0f / (1.0f + ex);
    t2i[b * 2 + 0] = i0; t2i[b * 2 + 1] = i1;
    t2w[b * 2 + 0] = w0; t2w[b * 2 + 1] = ex * w0;
}

// ---------------- gating: 2 tokens per wave (gw row reuse), fp64 accumulation ----------------
__global__ void __launch_bounds__(256) gate_kernel(XPtrs xs, const float* __restrict__ gw,
                                                   const float* __restrict__ gb,
                                                   int* __restrict__ t2i, float* __restrict__ t2w) {
    int wave = threadIdx.x >> 6;
    int lane = threadIdx.x & 63;
    int b0 = blockIdx.x * 8 + wave * 2;
    double acc0[8], acc1[8];
#pragma unroll
    for (int e = 0; e < 8; ++e) { acc0[e] = 0.0; acc1[e] = 0.0; }
    for (int ep = 0; ep < 8; ++ep) {
        const float* xr0 = xs.p[ep] + (size_t)b0 * D_;
        const float* xr1 = xr0 + D_;
        for (int t = 0; t < D_ / 64; ++t) {
            int d = t * 64 + lane;
            float v0 = xr0[d];
            float v1 = xr1[d];
            const float* g = gw + ((size_t)(ep * D_ + d)) * 8;
#pragma unroll
            for (int e = 0; e < 8; ++e) {
                double ge = (double)g[e];
                acc0[e] += (double)v0 * ge;
                acc1[e] += (double)v1 * ge;
            }
        }
    }
#pragma unroll
    for (int e = 0; e < 8; ++e) {
        for (int off = 32; off > 0; off >>= 1) {
            acc0[e] += __shfl_xor(acc0[e], off, 64);
            acc1[e] += __shfl_xor(acc1[e], off, 64);
        }
    }
    if (lane == 0) {
        gate_finish(b0 + 0, acc0, gb, t2i, t2w);
        gate_finish(b0 + 1, acc1, gb, t2i, t2w);
    }
}

// ---------------- routing: counts -> offsets (single block) ----------------
__global__ void __launch_bounds__(256) route_build(const int* __restrict__ t2i,
                                                   int* __restrict__ offs, int* __restrict__ cursor) {
    __shared__ int cnt[8];
    int t = threadIdx.x;
    if (t < 8) cnt[t] = 0;
    __syncthreads();
    for (int i = t; i < B_ * 2; i += 256) atomicAdd(&cnt[t2i[i]], 1);
    __syncthreads();
    if (t == 0) {
        int run = 0;
        for (int e = 0; e < 8; ++e) { offs[e] = run; cursor[e] = run; run += cnt[e]; }
        offs[8] = run;
    }
}

// ---------------- fused scatter + gather ----------------
__global__ void __launch_bounds__(256) scatter_gather(XPtrs xs, const int* __restrict__ t2i,
                                                      int* __restrict__ cursor, int* __restrict__ slot,
                                                      u16* __restrict__ A1) {
    int b = blockIdx.x;
    int t = threadIdx.x;
    __shared__ int gsh[2];
    int e0 = t2i[b * 2 + 0], e1 = t2i[b * 2 + 1];
    if (t == 0) {
        int g0 = atomicAdd(&cursor[e0], 1);
        int g1 = atomicAdd(&cursor[e1], 1);
        gsh[0] = g0; gsh[1] = g1;
        slot[b * 2 + 0] = g0; slot[b * 2 + 1] = g1;
    }
    __syncthreads();
    int g0 = gsh[0], g1 = gsh[1];
    float4 v0 = ((const float4*)(xs.p[e0] + (size_t)b * D_))[t];
    float4 v1 = ((const float4*)(xs.p[e1] + (size_t)b * D_))[t];
    u16x4 o0, o1;
    o0.x = f2bf(v0.x); o0.y = f2bf(v0.y); o0.z = f2bf(v0.z); o0.w = f2bf(v0.w);
    o1.x = f2bf(v1.x); o1.y = f2bf(v1.y); o1.z = f2bf(v1.z); o1.w = f2bf(v1.w);
    ((u16x4*)(A1 + (size_t)g0 * D_))[t] = o0;
    ((u16x4*)(A1 + (size_t)g1 * D_))[t] = o1;
}

// ---------------- weight transpose-convert: [E][K][N] f32 -> [E][N][K] bf16 ----------------
__global__ void __launch_bounds__(256) wconv(const float* __restrict__ w, u16* __restrict__ wt,
                                             int K, int N) {
    __shared__ float tile[64][33];
    int e = blockIdx.z;
    int n0 = blockIdx.x * 32, k0 = blockIdx.y * 64;
    int tid = threadIdx.x;
    int tx = tid & 31, ty = tid >> 5;
    const float* wp = w + (size_t)e * K * N + (size_t)k0 * N + n0;
#pragma unroll
    for (int r = 0; r < 8; ++r)
        tile[ty + r * 8][tx] = wp[(size_t)(ty + r * 8) * N + tx];
    __syncthreads();
    int n = tid >> 3, kq = tid & 7;
    u16x8 o;
#pragma unroll
    for (int i = 0; i < 8; ++i) o[i] = f2bf(tile[kq * 8 + i][n]);
    u16* op = wt + (size_t)e * N * K + (size_t)(n0 + n) * K + k0 + kq * 8;
    *(u16x8*)op = o;
}

// ============ 256x256 8-phase expert GEMM v2.1: register-pipelined frags ============
// v2 (R8) FAILED: tail iterations skip stages but kept steady-state vmcnt counts.
// At T=NT-2 the mid vmcnt(8) saw only 8 outstanding (waits for nothing) -> pre-reads
// of A0/B0(NT-1) raced their DMAs; at T=NT-1, P1/P2 read {A1,B1}(NT-1) still in
// flight. absmax 0.104. v2.1 fix: for T+2>=NT use FULL vm drain at the mid-wait
// (0x70) and vmcnt(0)-lgkm-free (0xF70) at the end-wait. Steady state unchanged:
//   P1: MFMA(A0,B0) | read B1(T)   | stage A1(T+1)
//   P2: MFMA(A0,B1) | read A1(T)   | stage B1(T+1)
//   P3: MFMA(A1,B0) |              | stage A0(T+2)
//   P4: stage B0(T+2); vmcnt(8)+bar; read A0,B0(T+1); MFMA(A1,B1); vmcnt(4) lgkm-free; bar
// Steady ledger/thread (2 loads/stage): enter=4 {A0,B0}(T+1); +8 across P1-P4 = 12;
// mid vmcnt(8) retires {A0,B0}(T+1); end vmcnt(4) retires {A1,B1}(T+1) -> enter
// next = 4. Tail walked exhaustively for T=NT-3..NT-1 (r8, r9).
__global__ void __launch_bounds__(512, 2) expert_gemm256(const u16* __restrict__ A,
                                                         const u16* __restrict__ Wt,
                                                         const float* __restrict__ bias,
                                                         u16* __restrict__ outB,
                                                         const int* __restrict__ offs,
                                                         int K, int N) {
    int bid = blockIdx.x;
    int e = bid & 7;                     // XCD affinity: expert e -> XCD e
    int j = bid >> 3;
    int mt = j & (MT256 - 1);
    int nt = j >> 3;
    int row0 = offs[e];
    int cnt = offs[e + 1] - row0;
    if (mt * 256 >= cnt) return;

    extern __shared__ __align__(16) u16 smem[];
    u16* sA = smem;                      // 2dbuf x 2half x 128 x 64 bf16 (64KB)
    u16* sB = smem + 32768;

    int tid = threadIdx.x;
    int wave = tid >> 6, lane = tid & 63;
    int wm = wave >> 2;                  // 0..1  (M dim)
    int wn = wave & 3;                   // 0..3  (N dim)
    int l15 = lane & 15, quad = lane >> 4;
    int swz = l15 & 7;                   // read-side row XOR for chunk swizzle

    const u16* Abase = A + (size_t)(row0 + mt * 256) * K;
    const u16* Bbase = Wt + ((size_t)e * N + (size_t)nt * 256) * K;
    int NT = K >> 6;                     // K-tiles of 64

    auto stageA = [&](int tile, int half) {
        if (tile < NT) {
            u16* dst = sA + (((tile & 1) * 2 + half) << 13);
            const u16* gs = Abase + (size_t)(half * 128) * K + tile * 64;
#pragma unroll
            for (int rr = 0; rr < 2; ++rr) {
                int liB = rr * 512 + wave * 64;          // wave-uniform
                int li = liB + lane;
                int r = li >> 3;
                int lc = (li & 7) ^ (r & 7);
                gl2lds16(gs + (size_t)r * K + lc * 8, dst + liB * 8);
            }
        }
    };
    auto stageB = [&](int tile, int half) {
        if (tile < NT) {
            u16* dst = sB + (((tile & 1) * 2 + half) << 13);
            const u16* gs = Bbase + (size_t)(half * 128) * K + tile * 64;
#pragma unroll
            for (int rr = 0; rr < 2; ++rr) {
                int liB = rr * 512 + wave * 64;
                int li = liB + lane;
                int r = li >> 3;
                int lc = (li & 7) ^ (r & 7);
                gl2lds16(gs + (size_t)r * K + lc * 8, dst + liB * 8);
            }
        }
    };

    bf16x8 afA[4][2], afB[4][2];         // A-half frag sets
    bf16x8 bf0[2][2], bf1[2][2];         // B-half frag sets

    auto readA = [&](bf16x8 (&dst)[4][2], const u16* base) {
#pragma unroll
        for (int fm = 0; fm < 4; ++fm) {
            int rh = wm * 64 + fm * 16 + l15;
#pragma unroll
            for (int kc = 0; kc < 2; ++kc)
                dst[fm][kc] = *(const bf16x8*)(base + rh * 64 + (((kc << 2) | quad) ^ swz) * 8);
        }
    };
    auto readB = [&](bf16x8 (&dst)[2][2], const u16* base) {
#pragma unroll
        for (int fn = 0; fn < 2; ++fn) {
            int rh = wn * 32 + fn * 16 + l15;
#pragma unroll
            for (int kc = 0; kc < 2; ++kc)
                dst[fn][kc] = *(const bf16x8*)(base + rh * 64 + (((kc << 2) | quad) ^ swz) * 8);
        }
    };
    auto mfmaQ = [&](bf16x8 (&a)[4][2], bf16x8 (&b)[2][2], f32x4 (&ac)[4][2]) {
        __builtin_amdgcn_s_setprio(1);
#pragma unroll
        for (int fm = 0; fm < 4; ++fm)
#pragma unroll
            for (int fn = 0; fn < 2; ++fn)
#pragma unroll
                for (int kc = 0; kc < 2; ++kc)
                    ac[fm][fn] = __builtin_amdgcn_mfma_f32_16x16x32_bf16(
                        a[fm][kc], b[fn][kc], ac[fm][fn], 0, 0, 0);
        __builtin_amdgcn_s_setprio(0);
    };

    f32x4 acc[2][2][4][2];
#pragma unroll
    for (int a = 0; a < 2; ++a)
#pragma unroll
        for (int b = 0; b < 2; ++b)
#pragma unroll
            for (int c = 0; c < 4; ++c)
#pragma unroll
                for (int dd = 0; dd < 2; ++dd) acc[a][b][c][dd] = (f32x4){0.f, 0.f, 0.f, 0.f};

    // prologue: tile0 (4 halves) + tile1 {A0,B0}; land tile0 {A0,B0}; preload regs;
    // land tile0 {A1,B1}; invariant entering loop: outstanding = {A0,B0}(1) = 4.
    stageA(0, 0); stageB(0, 0); stageA(0, 1); stageB(0, 1);
    stageA(1, 0); stageB(1, 0);
    __builtin_amdgcn_s_waitcnt(0x78);    // vmcnt(8) lgkm(0)
    __builtin_amdgcn_s_barrier();
    readA(afA, sA);                      // A0(0), dbuf0 half0
    readB(bf0, sB);                      // B0(0)
    __builtin_amdgcn_s_waitcnt(0xF74);   // vmcnt(4), lgkm free-running
    __builtin_amdgcn_s_barrier();

    for (int T = 0; T < NT; ++T) {
        int d = T & 1, dn = d ^ 1;
        const u16* aB1p = sA + ((d * 2 + 1) << 13);
        const u16* bB1p = sB + ((d * 2 + 1) << 13);
        const u16* aB0n = sA + ((dn * 2 + 0) << 13);
        const u16* bB0n = sB + ((dn * 2 + 0) << 13);
        int steady = (T + 2 < NT);       // all 4 stages issued this iteration

        // P1: read B1(T) (for P2); stage A1(T+1); MFMA (A0,B0)
        readB(bf1, bB1p);
        stageA(T + 1, 1);
        __builtin_amdgcn_s_barrier();
        mfmaQ(afA, bf0, acc[0][0]);
        __builtin_amdgcn_s_barrier();

        // P2: read A1(T) (for P3); stage B1(T+1); MFMA (A0,B1)
        readA(afB, aB1p);
        stageB(T + 1, 1);
        __builtin_amdgcn_s_barrier();
        mfmaQ(afA, bf1, acc[0][1]);
        __builtin_amdgcn_s_barrier();

        // P3: stage A0(T+2); MFMA (A1,B0)
        stageA(T + 2, 0);
        __builtin_amdgcn_s_barrier();
        mfmaQ(afB, bf0, acc[1][0]);
        __builtin_amdgcn_s_barrier();

        // P4: stage B0(T+2); mid-wait+bar -> {A0,B0}(T+1) landed for ALL waves;
        //     read next-tile A0,B0 into dead sets; MFMA (A1,B1); end-wait; bar.
        stageB(T + 2, 0);
        if (steady) __builtin_amdgcn_s_waitcnt(0x78);   // vmcnt(8) lgkm(0): retires {A0,B0}(T+1)
        else        __builtin_amdgcn_s_waitcnt(0x70);   // TAIL: stages skipped -> counts off; full vm drain
        __builtin_amdgcn_s_barrier();
        if (T + 1 < NT) {
            readA(afA, aB0n);
            readB(bf0, bB0n);
        }
        mfmaQ(afB, bf1, acc[1][1]);
        if (steady) __builtin_amdgcn_s_waitcnt(0xF74);  // vmcnt(4), lgkm free (protect new reads)
        else        __builtin_amdgcn_s_waitcnt(0xF70);  // TAIL: vm drain, lgkm free
        __builtin_amdgcn_s_barrier();
    }
    __builtin_amdgcn_s_waitcnt(0x70);        // defensive drain before epilogue

    // epilogue: C/D layout col=lane&15, row=quad*4+reg; bias+relu, bf16 out
#pragma unroll
    for (int mh = 0; mh < 2; ++mh)
#pragma unroll
        for (int nh = 0; nh < 2; ++nh)
#pragma unroll
            for (int fn = 0; fn < 2; ++fn) {
                int col = nt * 256 + nh * 128 + wn * 32 + fn * 16 + l15;
                float bv = bias[e * N + col];
#pragma unroll
                for (int fm = 0; fm < 4; ++fm) {
                    int rloc = mt * 256 + mh * 128 + wm * 64 + fm * 16 + quad * 4;
#pragma unroll
                    for (int r = 0; r < 4; ++r) {
                        if (rloc + r < cnt) {
                            float v = acc[mh][nh][fm][fn][r] + bv;
                            v = fmaxf(v, 0.f);
                            outB[(size_t)(row0 + rloc + r) * N + col] = f2bf(v);
                        }
                    }
                }
            }
}

// ---------------- legacy 128x128 expert GEMM (kept for layer 3: N=1024) ----------------
__global__ void __launch_bounds__(256) expert_gemm(const u16* __restrict__ A, const u16* __restrict__ Wt,
                                                   const float* __restrict__ bias,
                                                   u16* __restrict__ outB, float* __restrict__ outF,
                                                   const int* __restrict__ offs, int K, int N, int relu) {
    int bid = blockIdx.x;
    int e = bid & 7;
    int j = bid >> 3;
    int mt = j & (MT_MAX - 1);
    int nt = j >> 4;
    int row0 = offs[e];
    int cnt = offs[e + 1] - row0;
    if (mt * 128 >= cnt) return;

    __shared__ __align__(16) u16 sA[3][128 * 32];
    __shared__ __align__(16) u16 sB[3][128 * 32];

    int tid = threadIdx.x;
    int wave = tid >> 6, lane = tid & 63;
    int wm = wave & 1, wn = wave >> 1;
    int l15 = lane & 15, quad = lane >> 4;
    int rsub = lane >> 2;
    int koff = (((lane & 3) ^ (rsub & 3) ^ ((rsub >> 2) & 3)) * 8);
    int physOff = (quad ^ (l15 & 3) ^ ((l15 >> 2) & 3)) * 8;

    f32x4 acc[4][4];
#pragma unroll
    for (int i = 0; i < 4; ++i)
#pragma unroll
        for (int jj = 0; jj < 4; ++jj) acc[i][jj] = (f32x4){0.f, 0.f, 0.f, 0.f};

    const u16* Abase = A + (size_t)(row0 + mt * 128) * K;
    const u16* Bbase = Wt + ((size_t)e * N + (size_t)nt * 128) * K;

    int kSteps = K / 32;

    auto issue = [&](int ks, int bufIdx) {
        int k0 = ks * 32;
        u16* dA = &sA[bufIdx][0];
        u16* dB = &sB[bufIdx][0];
#pragma unroll
        for (int c = 0; c < 2; ++c) {
            int ch = wave * 2 + c;
            int r = ch * 16 + rsub;
            gl2lds16(Abase + (size_t)r * K + k0 + koff, dA + ch * 512);
            gl2lds16(Bbase + (size_t)r * K + k0 + koff, dB + ch * 512);
        }
    };

    issue(0, 0);
    issue(1, 1);
    int bc = 0, bi = 2;
    for (int ks = 0; ks < kSteps; ++ks) {
        if (ks + 1 < kSteps) __builtin_amdgcn_s_waitcnt(0x74);
        else                 __builtin_amdgcn_s_waitcnt(0x70);
        __builtin_amdgcn_s_barrier();
        if (ks + 2 < kSteps) issue(ks + 2, bi);

        const u16* a_ = &sA[bc][0];
        const u16* b_ = &sB[bc][0];
        bf16x8 af[4], bfr[4];
#pragma unroll
        for (int tm = 0; tm < 4; ++tm) {
            int row = wm * 64 + tm * 16 + l15;
            af[tm] = *(const bf16x8*)(a_ + row * 32 + physOff);
        }
#pragma unroll
        for (int tn = 0; tn < 4; ++tn) {
            int row = wn * 64 + tn * 16 + l15;
            bfr[tn] = *(const bf16x8*)(b_ + row * 32 + physOff);
        }
        __builtin_amdgcn_s_setprio(1);
#pragma unroll
        for (int tm = 0; tm < 4; ++tm)
#pragma unroll
            for (int tn = 0; tn < 4; ++tn)
                acc[tm][tn] = __builtin_amdgcn_mfma_f32_16x16x32_bf16(af[tm], bfr[tn], acc[tm][tn], 0, 0, 0);
        __builtin_amdgcn_s_setprio(0);

        bc = (bc == 2) ? 0 : bc + 1;
        bi = (bi == 2) ? 0 : bi + 1;
    }

    size_t gm0 = (size_t)row0 + (size_t)mt * 128 + (size_t)wm * 64;
    int lm0 = mt * 128 + wm * 64;
    int n0 = nt * 128 + wn * 64;
#pragma unroll
    for (int tn = 0; tn < 4; ++tn) {
        int col = n0 + tn * 16 + l15;
        float bv = bias[e * N + col];
#pragma unroll
        for (int tm = 0; tm < 4; ++tm) {
#pragma unroll
            for (int r = 0; r < 4; ++r) {
                int rr = tm * 16 + quad * 4 + r;
                if (lm0 + rr < cnt) {
                    float v = acc[tm][tn][r] + bv;
                    if (relu) v = fmaxf(v, 0.f);
                    if (outB) outB[(gm0 + rr) * N + col] = f2bf(v);
                    else      outF[(gm0 + rr) * N + col] = v;
                }
            }
        }
    }
}

// ---------------- combine: out[b] = w0*eo[slot0] + w1*eo[slot1] ----------------
__global__ void __launch_bounds__(256) combine_out(const float* __restrict__ eo, const int* __restrict__ slot,
                                                   const float* __restrict__ t2w, float* __restrict__ out) {
    int b = blockIdx.x, t = threadIdx.x;
    int g0 = slot[b * 2 + 0], g1 = slot[b * 2 + 1];
    float w0 = t2w[b * 2 + 0], w1 = t2w[b * 2 + 1];
    float4 va = ((const float4*)(eo + (size_t)g0 * O_))[t];
    float4 vc = ((const float4*)(eo + (size_t)g1 * O_))[t];
    float4 r;
    r.x = w0 * va.x + w1 * vc.x;
    r.y = w0 * va.y + w1 * vc.y;
    r.z = w0 * va.z + w1 * vc.z;
    r.w = w0 * va.w + w1 * vc.w;
    ((float4*)(out + (size_t)b * O_))[t] = r;
}

extern "C" void kernel_launch(void* const* d_in, const int* in_sizes, int n_in,
                              void* d_out, int out_size, void* d_ws, size_t ws_size,
                              hipStream_t stream) {
    (void)in_sizes; (void)n_in; (void)out_size; (void)ws_size;

    // one-time: raise dynamic-LDS cap for the 128KB kernel (default cap is 64KB).
    static bool lds_attr_set = false;
    if (!lds_attr_set) {
        hipFuncSetAttribute((const void*)expert_gemm256,
                            hipFuncAttributeMaxDynamicSharedMemorySize, 131072);
        lds_attr_set = true;
    }

    XPtrs xp;
    for (int i = 0; i < 8; ++i) xp.p[i] = (const float*)d_in[i];
    const float* gate_w = (const float*)d_in[8];
    const float* gate_b = (const float*)d_in[9];
    const float* w_in  = (const float*)d_in[10];
    const float* b_in  = (const float*)d_in[11];
    const float* w_h   = (const float*)d_in[12];
    const float* b_h   = (const float*)d_in[13];
    const float* w_out = (const float*)d_in[14];
    const float* b_out = (const float*)d_in[15];
    float* out = (float*)d_out;

    char* ws = (char*)d_ws;
    size_t off = 0;
    auto alloc = [&](size_t b) { size_t o = off; off += (b + 255) & ~(size_t)255; return o; };

    size_t t2i_o  = alloc((size_t)B_ * 2 * 4);
    size_t t2w_o  = alloc((size_t)B_ * 2 * 4);
    size_t slot_o = alloc((size_t)B_ * 2 * 4);
    size_t offs_o = alloc(16 * 4);
    size_t cur_o  = alloc(8 * 4);
    size_t A1_o   = alloc((size_t)GPAD * D_ * 2);      // bf16 gathered inputs
    size_t h1_o   = alloc((size_t)GPAD * H_ * 2);      // bf16
    size_t h2_o   = alloc((size_t)GPAD * H_ * 2);      // bf16
    size_t wtin_o = alloc((size_t)E_ * H_ * D_ * 2);   // bf16 [e][n][k]
    size_t wth_o  = alloc((size_t)E_ * H_ * H_ * 2);
    size_t wtout_o= alloc((size_t)E_ * O_ * H_ * 2);
    size_t eo_o   = A1_o;   // alias: A1+h1 dead by the time layer-3 writes eo

    int*   t2i  = (int*)(ws + t2i_o);
    float* t2w  = (float*)(ws + t2w_o);
    int*   slot = (int*)(ws + slot_o);
    int*   offs = (int*)(ws + offs_o);
    int*   cur  = (int*)(ws + cur_o);
    u16*   A1   = (u16*)(ws + A1_o);
    u16*   h1   = (u16*)(ws + h1_o);
    u16*   h2   = (u16*)(ws + h2_o);
    u16*   wtin = (u16*)(ws + wtin_o);
    u16*   wth  = (u16*)(ws + wth_o);
    u16*   wtout= (u16*)(ws + wtout_o);
    float* eo   = (float*)(ws + eo_o);

    // gating + routing (scatter+gather fused)
    hipLaunchKernelGGL(gate_kernel, dim3(B_ / 8), dim3(256), 0, stream, xp, gate_w, gate_b, t2i, t2w);
    hipLaunchKernelGGL(route_build, dim3(1), dim3(256), 0, stream, t2i, offs, cur);
    hipLaunchKernelGGL(scatter_gather, dim3(B_), dim3(256), 0, stream, xp, t2i, cur, slot, A1);

    // weight convert+transpose (fp32 [E][K][N] -> bf16 [E][N][K])
    hipLaunchKernelGGL(wconv, dim3(H_ / 32, D_ / 64, E_), dim3(256), 0, stream, w_in, wtin, D_, H_);
    hipLaunchKernelGGL(wconv, dim3(H_ / 32, H_ / 64, E_), dim3(256), 0, stream, w_h, wth, H_, H_);
    hipLaunchKernelGGL(wconv, dim3(O_ / 32, H_ / 64, E_), dim3(256), 0, stream, w_out, wtout, H_, O_);

    // expert MLP: layers 1+2 on the 256^2 v2.1 kernel, layer 3 on legacy 128^2.
    hipLaunchKernelGGL(expert_gemm256, dim3(E_ * MT256 * (H_ / 256)), dim3(512), 131072, stream,
                       A1, wtin, b_in, h1, offs, D_, H_);
    hipLaunchKernelGGL(expert_gemm256, dim3(E_ * MT256 * (H_ / 256)), dim3(512), 131072, stream,
                       h1, wth, b_h, h2, offs, H_, H_);
    hipLaunchKernelGGL(expert_gemm, dim3(E_ * MT_MAX * (O_ / 128)), dim3(256), 0, stream,
                       h2, wtout, b_out, (u16*)nullptr, eo, offs, H_, O_, 0);

    // weighted combine -> out (fully written, no zero-init needed)
    hipLaunchKernelGGL(combine_out, dim3(B_), dim3(256), 0, stream, eo, slot, t2w, out);
}